// Round 2
// baseline (1199.148 us; speedup 1.0000x reference)
//
#include <hip/hip_runtime.h>
#include <math.h>

#define Bc 8
#define Sc 512
#define Hc 512
#define NHc 8
#define HDc 64
#define DISc 32
#define S2c 1024

// ---------------------------------------------------------------------------
// C[M,N] = A[M,K] @ B[N,K]^T   (torch Linear convention), fp32, 64x64 tiles
// grid (N/64, M/64), block 256
// ---------------------------------------------------------------------------
__global__ __launch_bounds__(256) void gemm_nt_k(const float* __restrict__ A,
                                                 const float* __restrict__ Bm,
                                                 float* __restrict__ C,
                                                 int M, int N, int K) {
  const int t = threadIdx.x;
  const int tx = t & 15, ty = t >> 4;
  const int m0 = blockIdx.y << 6, n0 = blockIdx.x << 6;
  __shared__ float As[16][64];
  __shared__ float Bs[16][64];
  float acc[4][4] = {};
  const int lr = t >> 2, lc = (t & 3) << 2;
  for (int k0 = 0; k0 < K; k0 += 16) {
    float4 av = *(const float4*)(A + (size_t)(m0 + lr) * K + k0 + lc);
    float4 bv = *(const float4*)(Bm + (size_t)(n0 + lr) * K + k0 + lc);
    As[lc + 0][lr] = av.x; As[lc + 1][lr] = av.y; As[lc + 2][lr] = av.z; As[lc + 3][lr] = av.w;
    Bs[lc + 0][lr] = bv.x; Bs[lc + 1][lr] = bv.y; Bs[lc + 2][lr] = bv.z; Bs[lc + 3][lr] = bv.w;
    __syncthreads();
#pragma unroll
    for (int kk = 0; kk < 16; ++kk) {
      float4 a4 = *(const float4*)&As[kk][ty << 2];
      float4 b4 = *(const float4*)&Bs[kk][tx << 2];
      float aa[4] = {a4.x, a4.y, a4.z, a4.w};
      float bb[4] = {b4.x, b4.y, b4.z, b4.w};
#pragma unroll
      for (int i = 0; i < 4; ++i)
#pragma unroll
        for (int j = 0; j < 4; ++j)
          acc[i][j] = fmaf(aa[i], bb[j], acc[i][j]);
    }
    __syncthreads();
  }
#pragma unroll
  for (int i = 0; i < 4; ++i) {
    float4 o = make_float4(acc[i][0], acc[i][1], acc[i][2], acc[i][3]);
    *(float4*)(C + (size_t)(m0 + (ty << 2) + i) * N + n0 + (tx << 2)) = o;
  }
}

// ---------------------------------------------------------------------------
// Pos-weight tables:
// out[((b*NH+h)*R + r)*32 + n] = sum_d rows[(b*R+r)*512 + h*64+d] * emb[n*512 + h*64+d]
// grid: B * NH * (R/64), block 256. One block = 64 rows x 32 dist-buckets for one (b,h).
// ---------------------------------------------------------------------------
__global__ __launch_bounds__(256) void posw_k(const float* __restrict__ rows,
                                              const float* __restrict__ emb,
                                              float* __restrict__ out, int R) {
  const int t = threadIdx.x;
  const int tiles = R >> 6;
  const int rt = blockIdx.x % tiles;
  const int h = (blockIdx.x / tiles) & 7;
  const int b = blockIdx.x / (tiles * 8);
  __shared__ float es[32][65];   // emb slice [n][d], padded
  __shared__ float xs[64][65];   // row slice [r][d], padded
#pragma unroll
  for (int i = 0; i < 2; ++i) {
    int f = t + (i << 8);                 // 512 float4s = 2048 floats
    int n = f >> 4, d4 = (f & 15) << 2;
    float4 v4 = *(const float4*)(emb + ((size_t)n << 9) + (h << 6) + d4);
    es[n][d4] = v4.x; es[n][d4 + 1] = v4.y; es[n][d4 + 2] = v4.z; es[n][d4 + 3] = v4.w;
  }
  const size_t row0 = (size_t)b * R + (rt << 6);
#pragma unroll
  for (int i = 0; i < 4; ++i) {
    int f = t + (i << 8);                 // 1024 float4s = 4096 floats
    int r = f >> 4, d4 = (f & 15) << 2;
    float4 v4 = *(const float4*)(rows + (row0 + r) * 512 + (h << 6) + d4);
    xs[r][d4] = v4.x; xs[r][d4 + 1] = v4.y; xs[r][d4 + 2] = v4.z; xs[r][d4 + 3] = v4.w;
  }
  __syncthreads();
  const int n = t & 31;
  const int rs0 = (t >> 5) << 3;          // 8 rows per thread-group
  for (int rr = 0; rr < 8; ++rr) {
    float s = 0.f;
#pragma unroll
    for (int d = 0; d < 64; ++d) s = fmaf(xs[rs0 + rr][d], es[n][d], s);
    out[((((size_t)b * 8 + h) * R) + (rt << 6) + rs0 + rr) * 32 + n] = s;
  }
}

// ---------------------------------------------------------------------------
// Fused attention: one block = (b, h, 4 consecutive queries). Wave w owns query
// s0+w; lane L owns keys {kt*64+L}. Scores live in 16 registers per lane.
// grid: B*NH*(S/4) = 8192 (s fastest -> consecutive blocks share (b,h) K/V in L2)
// LDS ~20 KB: K/V tile (64x65) + per-tile prob buffer + q + qpw-row + vdw.
// ---------------------------------------------------------------------------
__global__ __launch_bounds__(256) void attn_k(
    const float* __restrict__ q_lin, const float* __restrict__ k_lin,
    const float* __restrict__ v_lin, const float* __restrict__ qpw,
    const float* __restrict__ kpw, const int* __restrict__ rel,
    const unsigned char* __restrict__ mask, const float* __restrict__ v_emb,
    float* __restrict__ attn_out) {
  const int bid = blockIdx.x;
  const int st = bid & 127;
  const int h = (bid >> 7) & 7;
  const int b = bid >> 10;
  const int s0 = st << 2;
  const int t = threadIdx.x;
  const int w = t >> 6;
  const int lane = t & 63;

  __shared__ float tile[64 * 65];    // K tile as [d][key] (QK), V tile as [key][d] (PV)
  __shared__ float pbuf[4][64];      // per-tile normalized probs
  __shared__ float qrow[4][64];
  __shared__ float q32[4][32];       // gathered qpw row per query
  __shared__ float vdw[4][32];       // distance-bucket scatter accumulators

  {
    int qi = t >> 6, d = t & 63;
    qrow[qi][d] = q_lin[((size_t)b * Sc + s0 + qi) * Hc + (h << 6) + d];
  }
  if (t < 128) {
    int qi = t >> 5, n = t & 31;
    q32[qi][n] = qpw[(((size_t)b * NHc + h) * Sc + s0 + qi) * 32 + n];
    vdw[qi][n] = 0.f;
  }
  __syncthreads();

  float qv[64];
#pragma unroll
  for (int d = 0; d < 64; ++d) qv[d] = qrow[w][d];

  const float* kb = k_lin + (size_t)b * (Sc * 1024);   // view [2S, 512]
  const float* vb = v_lin + (size_t)b * (Sc * 1024);

  float sarr[16];
  int rdarr[16];

  // ---- QK^T: 16 tiles of 64 keys; K staged transposed [d][key] (pad 65) ----
  for (int kt = 0; kt < 16; ++kt) {
#pragma unroll
    for (int i = 0; i < 4; ++i) {
      int f = t + (i << 8);
      int kk = f >> 4, c4 = (f & 15) << 2;
      float4 v4 = *(const float4*)(kb + (size_t)((kt << 6) + kk) * 512 + (h << 6) + c4);
      tile[(c4 + 0) * 65 + kk] = v4.x;
      tile[(c4 + 1) * 65 + kk] = v4.y;
      tile[(c4 + 2) * 65 + kk] = v4.z;
      tile[(c4 + 3) * 65 + kk] = v4.w;
    }
    __syncthreads();
    float s = 0.f;
#pragma unroll
    for (int d = 0; d < 64; ++d) s = fmaf(qv[d], tile[d * 65 + lane], s);
    sarr[kt] = s;
    __syncthreads();
  }

  // ---- add gathered pos weights, scale, mask (rel is int32 [B,S,2S]!) ----
  const int* relrow = rel + ((size_t)b * Sc + s0 + w) * S2c;
  const unsigned char* mrow = mask + ((size_t)b * Sc + s0 + w) * S2c;
  const float* kpw_bh = kpw + (((size_t)b * NHc + h) * S2c) * 32;
#pragma unroll
  for (int kt = 0; kt < 16; ++kt) {
    int key = (kt << 6) + lane;
    int rd = relrow[key];                                       // 0..31
    rdarr[kt] = rd;
    float val = (sarr[kt] + q32[w][rd] + kpw_bh[(size_t)key * 32 + rd]) * 0.125f;
    sarr[kt] = mrow[key] ? -INFINITY : val;
  }

  // ---- softmax over 1024 keys (registers + wave64 butterfly) + vdw scatter --
  {
    float m = -INFINITY;
#pragma unroll
    for (int kt = 0; kt < 16; ++kt) m = fmaxf(m, sarr[kt]);
#pragma unroll
    for (int off = 32; off > 0; off >>= 1) m = fmaxf(m, __shfl_xor(m, off));
    float l = 0.f;
#pragma unroll
    for (int kt = 0; kt < 16; ++kt) {
      float p = __expf(sarr[kt] - m);
      sarr[kt] = p;
      l += p;
    }
#pragma unroll
    for (int off = 32; off > 0; off >>= 1) l += __shfl_xor(l, off);
    float inv = 1.f / l;
#pragma unroll
    for (int kt = 0; kt < 16; ++kt) {
      float p = sarr[kt] * inv;
      sarr[kt] = p;
      atomicAdd(&vdw[w][rdarr[kt]], p);
    }
  }

  // ---- PV: V staged natural [key][d] (pad 65); lane owns output dim d=lane ----
  float out = 0.f;
  for (int kt = 0; kt < 16; ++kt) {
#pragma unroll
    for (int i = 0; i < 4; ++i) {
      int f = t + (i << 8);
      int kk = f >> 4, c4 = (f & 15) << 2;
      float4 v4 = *(const float4*)(vb + (size_t)((kt << 6) + kk) * 512 + (h << 6) + c4);
      tile[kk * 65 + c4 + 0] = v4.x;
      tile[kk * 65 + c4 + 1] = v4.y;
      tile[kk * 65 + c4 + 2] = v4.z;
      tile[kk * 65 + c4 + 3] = v4.w;
    }
    pbuf[w][lane] = sarr[kt];
    __syncthreads();
#pragma unroll
    for (int kk = 0; kk < 64; kk += 4) {
      float4 p4 = *(const float4*)&pbuf[w][kk];                 // broadcast read
      out = fmaf(p4.x, tile[(kk + 0) * 65 + lane], out);
      out = fmaf(p4.y, tile[(kk + 1) * 65 + lane], out);
      out = fmaf(p4.z, tile[(kk + 2) * 65 + lane], out);
      out = fmaf(p4.w, tile[(kk + 3) * 65 + lane], out);
    }
    __syncthreads();
  }

  // ---- + vdw @ v_emb (vdw complete: all waves passed the PV barriers) ----
#pragma unroll
  for (int n = 0; n < 32; ++n)
    out = fmaf(vdw[w][n], v_emb[((size_t)n << 9) + (h << 6) + lane], out);

  attn_out[((size_t)b * Sc + s0 + w) * Hc + (h << 6) + lane] = out;
}

// ---------------------------------------------------------------------------
extern "C" void kernel_launch(void* const* d_in, const int* in_sizes, int n_in,
                              void* d_out, int out_size, void* d_ws, size_t ws_size,
                              hipStream_t stream) {
  const float* x = (const float*)d_in[0];
  const int* rel = (const int*)d_in[1];                // int32 per harness contract
  const unsigned char* mask = (const unsigned char*)d_in[2];
  const float* qpe = (const float*)d_in[3];
  const float* kpe = (const float*)d_in[4];
  const float* vpe = (const float*)d_in[5];
  const float* Wq = (const float*)d_in[6];
  const float* Wk = (const float*)d_in[7];
  const float* Wv = (const float*)d_in[8];
  const float* Wo = (const float*)d_in[9];
  float* out = (float*)d_out;

  float* ws = (float*)d_ws;
  float* q_lin = ws;                      // [B*S, 512]        2,097,152 f
  float* k_lin = q_lin + 2097152;         // [B*2S, 512]       4,194,304 f
  float* v_lin = k_lin + 4194304;         // [B*2S, 512]       4,194,304 f
  float* qpw   = v_lin + 4194304;         // [B,NH,S,32]       1,048,576 f
  float* kpw   = qpw + 1048576;           // [B,NH,2S,32]      2,097,152 f
  float* attn  = kpw + 2097152;           // [B,S,512]         2,097,152 f
                                          // total 62.9 MB

  gemm_nt_k<<<dim3(8, 64), 256, 0, stream>>>(x, Wq, q_lin, 4096, 512, 512);
  gemm_nt_k<<<dim3(16, 64), 256, 0, stream>>>(x, Wk, k_lin, 4096, 1024, 512);
  gemm_nt_k<<<dim3(16, 64), 256, 0, stream>>>(x, Wv, v_lin, 4096, 1024, 512);
  posw_k<<<8 * 8 * 8, 256, 0, stream>>>(q_lin, qpe, qpw, 512);
  posw_k<<<8 * 8 * 16, 256, 0, stream>>>(k_lin, kpe, kpw, 1024);
  attn_k<<<8192, 256, 0, stream>>>(q_lin, k_lin, v_lin, qpw, kpw, rel, mask, vpe, attn);
  gemm_nt_k<<<dim3(8, 64), 256, 0, stream>>>(attn, Wo, out, 4096, 512, 512);
}

// Round 3
// 520.677 us; speedup vs baseline: 2.3031x; 2.3031x over previous
//
#include <hip/hip_runtime.h>
#include <math.h>

#define Bc 8
#define Sc 512
#define Hc 512
#define NHc 8
#define HDc 64
#define DISc 32
#define S2c 1024

typedef __attribute__((ext_vector_type(8))) short bf16x8;
typedef __attribute__((ext_vector_type(4))) float f32x4;
#define MFMA16(a, b, c) __builtin_amdgcn_mfma_f32_16x16x32_bf16(a, b, c, 0, 0, 0)

__device__ __forceinline__ unsigned short f2bf(float f) {
  unsigned u = __float_as_uint(f);
  return (unsigned short)((u + 0x7fffu + ((u >> 16) & 1u)) >> 16);  // RNE
}
__device__ __forceinline__ bf16x8 ldb16x8(const unsigned short* p) {
  union { uint4 u; bf16x8 s; } cv;
  cv.u = *(const uint4*)p;
  return cv.s;
}

// ---------------------------------------------------------------------------
// C[M,N] = A[M,K] @ B[N,K]^T, fp32, 64x64 tiles. grid (N/64, M/64), block 256
// ---------------------------------------------------------------------------
__global__ __launch_bounds__(256) void gemm_nt_k(const float* __restrict__ A,
                                                 const float* __restrict__ Bm,
                                                 float* __restrict__ C,
                                                 int M, int N, int K) {
  const int t = threadIdx.x;
  const int tx = t & 15, ty = t >> 4;
  const int m0 = blockIdx.y << 6, n0 = blockIdx.x << 6;
  __shared__ float As[16][64];
  __shared__ float Bs[16][64];
  float acc[4][4] = {};
  const int lr = t >> 2, lc = (t & 3) << 2;
  for (int k0 = 0; k0 < K; k0 += 16) {
    float4 av = *(const float4*)(A + (size_t)(m0 + lr) * K + k0 + lc);
    float4 bv = *(const float4*)(Bm + (size_t)(n0 + lr) * K + k0 + lc);
    As[lc + 0][lr] = av.x; As[lc + 1][lr] = av.y; As[lc + 2][lr] = av.z; As[lc + 3][lr] = av.w;
    Bs[lc + 0][lr] = bv.x; Bs[lc + 1][lr] = bv.y; Bs[lc + 2][lr] = bv.z; Bs[lc + 3][lr] = bv.w;
    __syncthreads();
#pragma unroll
    for (int kk = 0; kk < 16; ++kk) {
      float4 a4 = *(const float4*)&As[kk][ty << 2];
      float4 b4 = *(const float4*)&Bs[kk][tx << 2];
      float aa[4] = {a4.x, a4.y, a4.z, a4.w};
      float bb[4] = {b4.x, b4.y, b4.z, b4.w};
#pragma unroll
      for (int i = 0; i < 4; ++i)
#pragma unroll
        for (int j = 0; j < 4; ++j)
          acc[i][j] = fmaf(aa[i], bb[j], acc[i][j]);
    }
    __syncthreads();
  }
#pragma unroll
  for (int i = 0; i < 4; ++i) {
    float4 o = make_float4(acc[i][0], acc[i][1], acc[i][2], acc[i][3]);
    *(float4*)(C + (size_t)(m0 + (ty << 2) + i) * N + n0 + (tx << 2)) = o;
  }
}

// ---------------------------------------------------------------------------
// K projection: fp32 C (for posw) + bf16 copy in [b][h][k2][d] layout for attn.
// M=4096, N=1024, K=512. k2 = 2*s + (n>>9); h=(n>>6)&7; d=n&63.
// ---------------------------------------------------------------------------
__global__ __launch_bounds__(256) void gemm_nt_kb16(const float* __restrict__ A,
                                                    const float* __restrict__ Bm,
                                                    float* __restrict__ C,
                                                    unsigned short* __restrict__ kb16,
                                                    int M, int N, int K) {
  const int t = threadIdx.x;
  const int tx = t & 15, ty = t >> 4;
  const int m0 = blockIdx.y << 6, n0 = blockIdx.x << 6;
  __shared__ float As[16][64];
  __shared__ float Bs[16][64];
  float acc[4][4] = {};
  const int lr = t >> 2, lc = (t & 3) << 2;
  for (int k0 = 0; k0 < K; k0 += 16) {
    float4 av = *(const float4*)(A + (size_t)(m0 + lr) * K + k0 + lc);
    float4 bv = *(const float4*)(Bm + (size_t)(n0 + lr) * K + k0 + lc);
    As[lc + 0][lr] = av.x; As[lc + 1][lr] = av.y; As[lc + 2][lr] = av.z; As[lc + 3][lr] = av.w;
    Bs[lc + 0][lr] = bv.x; Bs[lc + 1][lr] = bv.y; Bs[lc + 2][lr] = bv.z; Bs[lc + 3][lr] = bv.w;
    __syncthreads();
#pragma unroll
    for (int kk = 0; kk < 16; ++kk) {
      float4 a4 = *(const float4*)&As[kk][ty << 2];
      float4 b4 = *(const float4*)&Bs[kk][tx << 2];
      float aa[4] = {a4.x, a4.y, a4.z, a4.w};
      float bb[4] = {b4.x, b4.y, b4.z, b4.w};
#pragma unroll
      for (int i = 0; i < 4; ++i)
#pragma unroll
        for (int j = 0; j < 4; ++j)
          acc[i][j] = fmaf(aa[i], bb[j], acc[i][j]);
    }
    __syncthreads();
  }
  const int bb = m0 >> 9, sb = (m0 & 511) + (ty << 2);
  const int e = n0 >> 9, hh = (n0 >> 6) & 7, d0 = tx << 2;
#pragma unroll
  for (int i = 0; i < 4; ++i) {
    float4 o = make_float4(acc[i][0], acc[i][1], acc[i][2], acc[i][3]);
    *(float4*)(C + (size_t)(m0 + (ty << 2) + i) * N + n0 + (tx << 2)) = o;
    int k2 = ((sb + i) << 1) + e;
    ushort4 u;
    u.x = f2bf(acc[i][0]); u.y = f2bf(acc[i][1]);
    u.z = f2bf(acc[i][2]); u.w = f2bf(acc[i][3]);
    *(ushort4*)(kb16 + ((size_t)((bb * 8 + hh) * 1024 + k2)) * 64 + d0) = u;
  }
}

// ---------------------------------------------------------------------------
// V projection: bf16 TRANSPOSED output only: vT16[b][h][d][k2].
// ---------------------------------------------------------------------------
__global__ __launch_bounds__(256) void gemm_nt_vt16(const float* __restrict__ A,
                                                    const float* __restrict__ Bm,
                                                    unsigned short* __restrict__ vT16,
                                                    int M, int N, int K) {
  const int t = threadIdx.x;
  const int tx = t & 15, ty = t >> 4;
  const int m0 = blockIdx.y << 6, n0 = blockIdx.x << 6;
  __shared__ float As[16][64];
  __shared__ float Bs[16][64];
  float acc[4][4] = {};
  const int lr = t >> 2, lc = (t & 3) << 2;
  for (int k0 = 0; k0 < K; k0 += 16) {
    float4 av = *(const float4*)(A + (size_t)(m0 + lr) * K + k0 + lc);
    float4 bv = *(const float4*)(Bm + (size_t)(n0 + lr) * K + k0 + lc);
    As[lc + 0][lr] = av.x; As[lc + 1][lr] = av.y; As[lc + 2][lr] = av.z; As[lc + 3][lr] = av.w;
    Bs[lc + 0][lr] = bv.x; Bs[lc + 1][lr] = bv.y; Bs[lc + 2][lr] = bv.z; Bs[lc + 3][lr] = bv.w;
    __syncthreads();
#pragma unroll
    for (int kk = 0; kk < 16; ++kk) {
      float4 a4 = *(const float4*)&As[kk][ty << 2];
      float4 b4 = *(const float4*)&Bs[kk][tx << 2];
      float aa[4] = {a4.x, a4.y, a4.z, a4.w};
      float bb[4] = {b4.x, b4.y, b4.z, b4.w};
#pragma unroll
      for (int i = 0; i < 4; ++i)
#pragma unroll
        for (int j = 0; j < 4; ++j)
          acc[i][j] = fmaf(aa[i], bb[j], acc[i][j]);
    }
    __syncthreads();
  }
  const int bb = m0 >> 9, e = n0 >> 9, hh = (n0 >> 6) & 7;
  unsigned short* base = vT16 + (size_t)(bb * 8 + hh) * 65536;
#pragma unroll
  for (int i = 0; i < 4; ++i) {
    int k2 = (((m0 & 511) + (ty << 2) + i) << 1) + e;
#pragma unroll
    for (int j = 0; j < 4; ++j)
      base[(size_t)((tx << 2) + j) * 1024 + k2] = f2bf(acc[i][j]);
  }
}

// ---------------------------------------------------------------------------
// Pos-weight tables (unchanged from R2; reads fp32 rows).
// ---------------------------------------------------------------------------
__global__ __launch_bounds__(256) void posw_k(const float* __restrict__ rows,
                                              const float* __restrict__ emb,
                                              float* __restrict__ out, int R) {
  const int t = threadIdx.x;
  const int tiles = R >> 6;
  const int rt = blockIdx.x % tiles;
  const int h = (blockIdx.x / tiles) & 7;
  const int b = blockIdx.x / (tiles * 8);
  __shared__ float es[32][65];
  __shared__ float xs[64][65];
#pragma unroll
  for (int i = 0; i < 2; ++i) {
    int f = t + (i << 8);
    int n = f >> 4, d4 = (f & 15) << 2;
    float4 v4 = *(const float4*)(emb + ((size_t)n << 9) + (h << 6) + d4);
    es[n][d4] = v4.x; es[n][d4 + 1] = v4.y; es[n][d4 + 2] = v4.z; es[n][d4 + 3] = v4.w;
  }
  const size_t row0 = (size_t)b * R + (rt << 6);
#pragma unroll
  for (int i = 0; i < 4; ++i) {
    int f = t + (i << 8);
    int r = f >> 4, d4 = (f & 15) << 2;
    float4 v4 = *(const float4*)(rows + (row0 + r) * 512 + (h << 6) + d4);
    xs[r][d4] = v4.x; xs[r][d4 + 1] = v4.y; xs[r][d4 + 2] = v4.z; xs[r][d4 + 3] = v4.w;
  }
  __syncthreads();
  const int n = t & 31;
  const int rs0 = (t >> 5) << 3;
  for (int rr = 0; rr < 8; ++rr) {
    float s = 0.f;
#pragma unroll
    for (int d = 0; d < 64; ++d) s = fmaf(xs[rs0 + rr][d], es[n][d], s);
    out[((((size_t)b * 8 + h) * R) + (rt << 6) + rs0 + rr) * 32 + n] = s;
  }
}

// ---------------------------------------------------------------------------
// Flash-style MFMA attention. Block = (b, h, 64 queries); 4 waves, wave w owns
// queries w*16..w*16+15 as one MFMA stripe. No online softmax: scores bounded
// (|s|<~9) so raw exp(s) cannot overflow fp32; normalize once at the end.
// Layouts (m89/m91-verified): A[m=lane&15][k=(lane>>4)*8+j],
// B^T-frag same indexing, D[row=(lane>>4)*4+reg][col=lane&15].
// grid = B*NH*(S/64) = 512 blocks (h fastest for rel-slice L2 sharing).
// ---------------------------------------------------------------------------
__global__ __launch_bounds__(256) void attn2_k(
    const float* __restrict__ q_lin, const unsigned short* __restrict__ kb16,
    const unsigned short* __restrict__ vT16, const float* __restrict__ qpw,
    const float* __restrict__ kpw, const int* __restrict__ rel,
    const unsigned char* __restrict__ mask, const float* __restrict__ v_emb,
    float* __restrict__ attn_out) {
  const int bid = blockIdx.x;
  const int h = bid & 7;
  const int qb = ((bid >> 3) & 7) << 6;
  const int b = bid >> 6;
  const int t = threadIdx.x;
  const int w = t >> 6;
  const int lane = t & 63;
  const int ln = lane & 15;
  const int qd = lane >> 4;

  __shared__ unsigned short Ks[64 * 72];     // K tile  [key][d]  bf16
  __shared__ unsigned short Vt[64 * 72];     // V tile  [d][key]  bf16 (pre-transposed src)
  __shared__ float kpws[64 * 36];            // kpw tile [key][n]
  __shared__ float q32s[64 * 36];            // qpw rows [q][n]
  __shared__ unsigned short pbuf[4][16 * 72];// P round-trip (C/D -> A layout)
  __shared__ float vdwm[4][16 * 36];         // raw exp sums per distance bucket
  __shared__ unsigned short vdwb[4][16 * 40];// vdw as bf16 A-frags
  __shared__ unsigned short vest[64 * 40];   // v_emb^T [d][n] bf16

  for (int i = t; i < 4 * 16 * 36; i += 256) ((float*)vdwm)[i] = 0.f;
  {  // q32s: 64 rows x 32 fp32
    const float* src = qpw + ((size_t)((b * 8 + h) * 512 + qb)) * 32;
#pragma unroll
    for (int p = 0; p < 2; ++p) {
      int id = t + (p << 8);
      int row = id >> 3, c4 = (id & 7) << 2;
      *(float4*)&q32s[row * 36 + c4] = *(const float4*)(src + row * 32 + c4);
    }
  }
  {  // vest: transpose v_emb[n][h*64+d] -> [d][n] bf16
    int n = t >> 3, d0 = (t & 7) << 3;
    const float* src = v_emb + ((size_t)n << 9) + (h << 6) + d0;
    float4 f0 = *(const float4*)src;
    float4 f1 = *(const float4*)(src + 4);
    vest[(d0 + 0) * 40 + n] = f2bf(f0.x); vest[(d0 + 1) * 40 + n] = f2bf(f0.y);
    vest[(d0 + 2) * 40 + n] = f2bf(f0.z); vest[(d0 + 3) * 40 + n] = f2bf(f0.w);
    vest[(d0 + 4) * 40 + n] = f2bf(f1.x); vest[(d0 + 5) * 40 + n] = f2bf(f1.y);
    vest[(d0 + 6) * 40 + n] = f2bf(f1.z); vest[(d0 + 7) * 40 + n] = f2bf(f1.w);
  }
  // Q A-frags held in registers for the whole kernel
  bf16x8 aQ[2];
  {
    const float* qsrc = q_lin + ((size_t)(b * 512 + qb + w * 16 + ln)) * 512 + (h << 6);
#pragma unroll
    for (int dc = 0; dc < 2; ++dc) {
      float4 f0 = *(const float4*)(qsrc + dc * 32 + qd * 8);
      float4 f1 = *(const float4*)(qsrc + dc * 32 + qd * 8 + 4);
      bf16x8 a;
      a[0] = (short)f2bf(f0.x); a[1] = (short)f2bf(f0.y);
      a[2] = (short)f2bf(f0.z); a[3] = (short)f2bf(f0.w);
      a[4] = (short)f2bf(f1.x); a[5] = (short)f2bf(f1.y);
      a[6] = (short)f2bf(f1.z); a[7] = (short)f2bf(f1.w);
      aQ[dc] = a;
    }
  }
  __syncthreads();

  f32x4 acc[4] = {{0.f, 0.f, 0.f, 0.f}, {0.f, 0.f, 0.f, 0.f},
                  {0.f, 0.f, 0.f, 0.f}, {0.f, 0.f, 0.f, 0.f}};

  const unsigned short* kbase = kb16 + ((size_t)(b * 8 + h)) * 65536;
  const unsigned short* vbase = vT16 + ((size_t)(b * 8 + h)) * 65536;
  const float* pbase = kpw + ((size_t)((b * 8 + h) * 1024)) * 32;
  const int* relp = rel + ((size_t)(b * 512 + qb + w * 16 + qd * 4)) * 1024;
  const unsigned char* mkp = mask + ((size_t)(b * 512 + qb + w * 16 + qd * 4)) * 1024;

  for (int kt = 0; kt < 16; ++kt) {
    const int kt0 = kt << 6;
    // ---- stage K/V/kpw tiles ----
#pragma unroll
    for (int p = 0; p < 2; ++p) {
      int id = t + (p << 8);
      int row = id >> 3, c8 = (id & 7) << 3;
      *(uint4*)&Ks[row * 72 + c8] = *(const uint4*)(kbase + (size_t)(kt0 + row) * 64 + c8);
      *(uint4*)&Vt[row * 72 + c8] = *(const uint4*)(vbase + (size_t)row * 1024 + kt0 + c8);
      int c4 = (id & 7) << 2;  // reuse id for kpw: 64 rows x 32 f32 = 512 float4
      if (p == 0)
        *(float4*)&kpws[row * 36 + c4] = *(const float4*)(pbase + (size_t)(kt0 + row) * 32 + c4);
      else
        *(float4*)&kpws[row * 36 + c4] = *(const float4*)(pbase + (size_t)(kt0 + row) * 32 + c4);
    }
    __syncthreads();

    // ---- QK^T: 4 S-tiles of 16 keys, K over d=64 (2 mfma each) ----
    f32x4 sc4[4];
#pragma unroll
    for (int t4 = 0; t4 < 4; ++t4) {
      f32x4 c = {0.f, 0.f, 0.f, 0.f};
      c = MFMA16(aQ[0], ldb16x8(&Ks[(t4 * 16 + ln) * 72 + qd * 8]), c);
      c = MFMA16(aQ[1], ldb16x8(&Ks[(t4 * 16 + ln) * 72 + 32 + qd * 8]), c);
      sc4[t4] = c;
    }

    // ---- pos-weights + scale + mask + exp; scatter to vdw; P -> pbuf ----
#pragma unroll
    for (int r = 0; r < 4; ++r) {
#pragma unroll
      for (int t4 = 0; t4 < 4; ++t4) {
        int kl = t4 * 16 + ln;
        int rd = relp[r * 1024 + kt0 + kl];
        float s = (sc4[t4][r] + q32s[(w * 16 + qd * 4 + r) * 36 + rd] +
                   kpws[kl * 36 + rd]) * 0.125f;
        float p = mkp[r * 1024 + kt0 + kl] ? 0.f : __expf(s);
        atomicAdd(&vdwm[w][(qd * 4 + r) * 36 + rd], p);
        pbuf[w][(qd * 4 + r) * 72 + kl] = f2bf(p);
      }
    }
    __syncthreads();

    // ---- PV: O += P(16x64) @ V(64x64) ----
    bf16x8 a0 = ldb16x8(&pbuf[w][ln * 72 + qd * 8]);
    bf16x8 a1 = ldb16x8(&pbuf[w][ln * 72 + 32 + qd * 8]);
#pragma unroll
    for (int dt = 0; dt < 4; ++dt) {
      acc[dt] = MFMA16(a0, ldb16x8(&Vt[(dt * 16 + ln) * 72 + qd * 8]), acc[dt]);
      acc[dt] = MFMA16(a1, ldb16x8(&Vt[(dt * 16 + ln) * 72 + 32 + qd * 8]), acc[dt]);
    }
    __syncthreads();
  }

  // ---- vdw -> bf16 A-frags; l = row-sum of vdw ----
  {
    int row = lane >> 2, n0 = (lane & 3) << 3;
    float4 v0 = *(const float4*)&vdwm[w][row * 36 + n0];
    float4 v1 = *(const float4*)&vdwm[w][row * 36 + n0 + 4];
    ushort4 u0, u1;
    u0.x = f2bf(v0.x); u0.y = f2bf(v0.y); u0.z = f2bf(v0.z); u0.w = f2bf(v0.w);
    u1.x = f2bf(v1.x); u1.y = f2bf(v1.y); u1.z = f2bf(v1.z); u1.w = f2bf(v1.w);
    *(ushort4*)&vdwb[w][row * 40 + n0] = u0;
    *(ushort4*)&vdwb[w][row * 40 + n0 + 4] = u1;
  }
  float inv[4];
#pragma unroll
  for (int r = 0; r < 4; ++r) {
    float l = 0.f;
#pragma unroll
    for (int n4 = 0; n4 < 8; ++n4) {
      float4 v = *(const float4*)&vdwm[w][(qd * 4 + r) * 36 + (n4 << 2)];
      l += v.x + v.y + v.z + v.w;
    }
    inv[r] = 1.f / l;
  }
  __syncthreads();

  // ---- O += vdw(16x32) @ v_emb(32x64), then normalize & store ----
  {
    bf16x8 av = ldb16x8(&vdwb[w][ln * 40 + qd * 8]);
#pragma unroll
    for (int dt = 0; dt < 4; ++dt)
      acc[dt] = MFMA16(av, ldb16x8(&vest[(dt * 16 + ln) * 40 + qd * 8]), acc[dt]);
  }
  float* obase = attn_out + ((size_t)(b * 512 + qb + w * 16 + qd * 4)) * 512 + (h << 6);
#pragma unroll
  for (int r = 0; r < 4; ++r)
#pragma unroll
    for (int dt = 0; dt < 4; ++dt)
      obase[(size_t)r * 512 + dt * 16 + ln] = acc[dt][r] * inv[r];
}

// ---------------------------------------------------------------------------
extern "C" void kernel_launch(void* const* d_in, const int* in_sizes, int n_in,
                              void* d_out, int out_size, void* d_ws, size_t ws_size,
                              hipStream_t stream) {
  const float* x = (const float*)d_in[0];
  const int* rel = (const int*)d_in[1];
  const unsigned char* mask = (const unsigned char*)d_in[2];
  const float* qpe = (const float*)d_in[3];
  const float* kpe = (const float*)d_in[4];
  const float* vpe = (const float*)d_in[5];
  const float* Wq = (const float*)d_in[6];
  const float* Wk = (const float*)d_in[7];
  const float* Wv = (const float*)d_in[8];
  const float* Wo = (const float*)d_in[9];
  float* out = (float*)d_out;

  float* ws = (float*)d_ws;
  float* q_lin = ws;                          // [B*S,512]        2,097,152 f
  float* k_lin = q_lin + 2097152;             // [B*2S,512]       4,194,304 f
  float* qpw   = k_lin + 4194304;             // [B,NH,S,32]      1,048,576 f
  float* kpw   = qpw + 1048576;               // [B,NH,2S,32]     2,097,152 f
  float* attn  = kpw + 2097152;               // [B,S,512]        2,097,152 f
  unsigned short* kb16 = (unsigned short*)(attn + 2097152);  // [B,NH,2S,64] bf16 (2M f-slots)
  unsigned short* vT16 = kb16 + 4194304;      // [B,NH,64,2S] bf16 (2M f-slots)
                                              // total 60 MB

  gemm_nt_k<<<dim3(8, 64), 256, 0, stream>>>(x, Wq, q_lin, 4096, 512, 512);
  gemm_nt_kb16<<<dim3(16, 64), 256, 0, stream>>>(x, Wk, k_lin, kb16, 4096, 1024, 512);
  gemm_nt_vt16<<<dim3(16, 64), 256, 0, stream>>>(x, Wv, vT16, 4096, 1024, 512);
  posw_k<<<8 * 8 * 8, 256, 0, stream>>>(q_lin, qpe, qpw, 512);
  posw_k<<<8 * 8 * 16, 256, 0, stream>>>(k_lin, kpe, kpw, 1024);
  attn2_k<<<512, 256, 0, stream>>>(q_lin, kb16, vT16, qpw, kpw, rel, mask, vpe, attn);
  gemm_nt_k<<<dim3(8, 64), 256, 0, stream>>>(attn, Wo, out, 4096, 512, 512);
}

// Round 4
// 367.431 us; speedup vs baseline: 3.2636x; 1.4171x over previous
//
#include <hip/hip_runtime.h>
#include <math.h>

#define Bc 8
#define Sc 512
#define Hc 512
#define NHc 8
#define HDc 64
#define DISc 32
#define S2c 1024

typedef __attribute__((ext_vector_type(8))) short bf16x8;
typedef __attribute__((ext_vector_type(4))) float f32x4;
#define MFMA16(a, b, c) __builtin_amdgcn_mfma_f32_16x16x32_bf16(a, b, c, 0, 0, 0)

__device__ __forceinline__ unsigned short f2bf(float f) {
  unsigned u = __float_as_uint(f);
  return (unsigned short)((u + 0x7fffu + ((u >> 16) & 1u)) >> 16);  // RNE
}
__device__ __forceinline__ float b2f(unsigned short u) {
  return __uint_as_float((unsigned)u << 16);
}
__device__ __forceinline__ bf16x8 ldb16x8(const unsigned short* p) {
  union { uint4 u; bf16x8 s; } cv;
  cv.u = *(const uint4*)p;
  return cv.s;
}

// ---------------------------------------------------------------------------
// fp32 -> bf16 conversions for x, Wq, Wk, Wv, Wo (one fused launch).
// group-of-4 counts: x 524288 | Wq 65536 | Wk 131072 | Wv 131072 | Wo 65536
// ---------------------------------------------------------------------------
__global__ __launch_bounds__(256) void cvt5_k(
    const float* __restrict__ x, const float* __restrict__ wq,
    const float* __restrict__ wk, const float* __restrict__ wv,
    const float* __restrict__ wo, unsigned short* __restrict__ x16,
    unsigned short* __restrict__ w16q, unsigned short* __restrict__ w16k,
    unsigned short* __restrict__ w16v, unsigned short* __restrict__ w16o) {
  int i = blockIdx.x * 256 + threadIdx.x;
  const float* src; unsigned short* dst; int off;
  if (i < 524288)      { src = x;  dst = x16;  off = i; }
  else if (i < 589824) { src = wq; dst = w16q; off = i - 524288; }
  else if (i < 720896) { src = wk; dst = w16k; off = i - 589824; }
  else if (i < 851968) { src = wv; dst = w16v; off = i - 720896; }
  else                 { src = wo; dst = w16o; off = i - 851968; }
  float4 v = ((const float4*)src)[off];
  ushort4 u;
  u.x = f2bf(v.x); u.y = f2bf(v.y); u.z = f2bf(v.z); u.w = f2bf(v.w);
  ((ushort4*)dst)[off] = u;
}

// ---------------------------------------------------------------------------
// bf16 MFMA GEMM: C[M,N] = A16[M,K] @ B16[N,K]^T, fp32 accumulate.
// 64x64 tile, BK=32, block 256 (4 waves 2x2, wave tile 32x32).
// MODE 0: fp32 C[m*N+n]           (Wo -> d_out)
// MODE 1: bf16 q16h[b][h][s][d]   (Q)
// MODE 2: bf16 kb16[b][h][k2][d]  (K, k2=2s+e)
// MODE 3: bf16 vT16[b][h][d][k2]  (V transposed)
// ---------------------------------------------------------------------------
template <int MODE>
__global__ __launch_bounds__(256, 4) void gemm16_k(
    const unsigned short* __restrict__ A, const unsigned short* __restrict__ B,
    void* __restrict__ outp, int M, int N, int K) {
  const int t = threadIdx.x;
  const int w = t >> 6, lane = t & 63, ln = lane & 15, qd = lane >> 4;
  const int wm = (w >> 1) << 5, wn = (w & 1) << 5;
  const int m0 = blockIdx.y << 6, n0 = blockIdx.x << 6;
  __shared__ unsigned short As[64 * 32];
  __shared__ unsigned short Bs[64 * 32];
  f32x4 z = {0.f, 0.f, 0.f, 0.f};
  f32x4 acc[2][2] = {{z, z}, {z, z}};
  const int srow = t >> 2, sc8 = (t & 3) << 3;
  for (int k0 = 0; k0 < K; k0 += 32) {
    *(uint4*)&As[srow * 32 + sc8] = *(const uint4*)(A + (size_t)(m0 + srow) * K + k0 + sc8);
    *(uint4*)&Bs[srow * 32 + sc8] = *(const uint4*)(B + (size_t)(n0 + srow) * K + k0 + sc8);
    __syncthreads();
    bf16x8 a0 = ldb16x8(&As[(wm + ln) * 32 + qd * 8]);
    bf16x8 a1 = ldb16x8(&As[(wm + 16 + ln) * 32 + qd * 8]);
    bf16x8 b0 = ldb16x8(&Bs[(wn + ln) * 32 + qd * 8]);
    bf16x8 b1 = ldb16x8(&Bs[(wn + 16 + ln) * 32 + qd * 8]);
    acc[0][0] = MFMA16(a0, b0, acc[0][0]);
    acc[0][1] = MFMA16(a0, b1, acc[0][1]);
    acc[1][0] = MFMA16(a1, b0, acc[1][0]);
    acc[1][1] = MFMA16(a1, b1, acc[1][1]);
    __syncthreads();
  }
#pragma unroll
  for (int tm = 0; tm < 2; ++tm)
#pragma unroll
    for (int tn = 0; tn < 2; ++tn)
#pragma unroll
      for (int r = 0; r < 4; ++r) {
        int m = m0 + wm + tm * 16 + qd * 4 + r;
        int n = n0 + wn + tn * 16 + ln;
        float v = acc[tm][tn][r];
        if (MODE == 0) {
          ((float*)outp)[(size_t)m * N + n] = v;
        } else {
          int bb = m >> 9, s = m & 511, hh = (n >> 6) & 7, d = n & 63;
          if (MODE == 1)
            ((unsigned short*)outp)[((size_t)(bb * 8 + hh) * 512 + s) * 64 + d] = f2bf(v);
          else if (MODE == 2) {
            int k2 = 2 * s + (n >> 9);
            ((unsigned short*)outp)[((size_t)(bb * 8 + hh) * 1024 + k2) * 64 + d] = f2bf(v);
          } else {
            int k2 = 2 * s + (n >> 9);
            ((unsigned short*)outp)[((size_t)(bb * 8 + hh) * 64 + d) * 1024 + k2] = f2bf(v);
          }
        }
      }
}

// ---------------------------------------------------------------------------
// Pos-weight tables from bf16 h-major rows:
// out[((b*8+h)*R + r)*32 + n] = sum_d rows16[((b*8+h)*R + r)*64 + d] * emb[n*512+h*64+d]
// ---------------------------------------------------------------------------
__global__ __launch_bounds__(256) void posw16_k(const unsigned short* __restrict__ rows16,
                                                const float* __restrict__ emb,
                                                float* __restrict__ out, int R) {
  const int t = threadIdx.x;
  const int tiles = R >> 6;
  const int rt = blockIdx.x % tiles;
  const int h = (blockIdx.x / tiles) & 7;
  const int b = blockIdx.x / (tiles * 8);
  __shared__ float es[32][65];
  __shared__ float xs[64][65];
#pragma unroll
  for (int i = 0; i < 2; ++i) {
    int f = t + (i << 8);
    int n = f >> 4, d4 = (f & 15) << 2;
    float4 v4 = *(const float4*)(emb + ((size_t)n << 9) + (h << 6) + d4);
    es[n][d4] = v4.x; es[n][d4 + 1] = v4.y; es[n][d4 + 2] = v4.z; es[n][d4 + 3] = v4.w;
  }
  const size_t row0 = (size_t)(b * 8 + h) * R + (rt << 6);
#pragma unroll
  for (int p = 0; p < 2; ++p) {
    int id = t + (p << 8);
    int r = id >> 3, c8 = (id & 7) << 3;
    uint4 u4 = *(const uint4*)(rows16 + (row0 + r) * 64 + c8);
    const unsigned short* us = (const unsigned short*)&u4;
#pragma unroll
    for (int j = 0; j < 8; ++j) xs[r][c8 + j] = b2f(us[j]);
  }
  __syncthreads();
  const int n = t & 31;
  const int rs0 = (t >> 5) << 3;
  for (int rr = 0; rr < 8; ++rr) {
    float s = 0.f;
#pragma unroll
    for (int d = 0; d < 64; ++d) s = fmaf(xs[rs0 + rr][d], es[n][d], s);
    out[((((size_t)b * 8 + h) * R) + (rt << 6) + rs0 + rr) * 32 + n] = s;
  }
}

// ---------------------------------------------------------------------------
// MFMA attention, split-K over wave groups. Block = (b,h,64 queries), 512 thr
// = 8 waves: waves 0-3 (g0) do kt 0..7, waves 4-7 (g1) do kt 8..15; partials
// combined via LDS. Scores bounded -> raw exp accumulate, normalize once.
// K/V/Q fragments load directly from global (L2). rel+mask staged packed.
// grid = B*NH*(S/64) = 512, h fastest.
// ---------------------------------------------------------------------------
__global__ __launch_bounds__(512, 4) void attn3_k(
    const unsigned short* __restrict__ q16h, const unsigned short* __restrict__ kb16,
    const unsigned short* __restrict__ vT16, const float* __restrict__ qpw,
    const float* __restrict__ kpw, const int* __restrict__ rel,
    const unsigned char* __restrict__ mask, const float* __restrict__ v_emb,
    unsigned short* __restrict__ attn16) {
  const int bid = blockIdx.x;
  const int h = bid & 7;
  const int qb = ((bid >> 3) & 7) << 6;
  const int b = bid >> 6;
  const int t = threadIdx.x;
  const int w = t >> 6;        // 0..7
  const int g = w >> 2;        // kt-half group
  const int ws4 = w & 3;       // query stripe
  const int lane = t & 63;
  const int ln = lane & 15;
  const int qd = lane >> 4;

  __shared__ __align__(16) char smem[58880];
  unsigned short* reltile = (unsigned short*)smem;             // 2 x (64x68) u
  unsigned short* kpws    = (unsigned short*)(smem + 17408);   // 2 x (64x36) u
  unsigned short* q32s    = (unsigned short*)(smem + 26624);   // 64x36 u
  unsigned short* pbuf    = (unsigned short*)(smem + 31232);   // 8 x (16x72) u
  float*          vdwm    = (float*)(smem + 49664);            // 4 x (16x36) f (shared per stripe)
  // endgame aliases (all source regions dead by then):
  float*          accbuf  = (float*)smem;                      // 4 x (16x68) f
  unsigned short* vest    = (unsigned short*)(smem + 31232);   // 64x40 u
  unsigned short* vdwb    = (unsigned short*)(smem + 36352);   // 4 x (16x40) u

  for (int i = t; i < 4 * 16 * 36; i += 512) vdwm[i] = 0.f;
  {  // q32s: 64 q x 32 n, fp32 -> bf16
    const float* src = qpw + ((size_t)((b * 8 + h) * 512 + qb)) * 32;
    int row = t >> 3, c4 = (t & 7) << 2;
    float4 v = *(const float4*)(src + row * 32 + c4);
    ushort4 u;
    u.x = f2bf(v.x); u.y = f2bf(v.y); u.z = f2bf(v.z); u.w = f2bf(v.w);
    *(ushort4*)&q32s[row * 36 + c4] = u;
  }
  const unsigned short* kbase = kb16 + (size_t)(b * 8 + h) * 65536;
  const unsigned short* vbase = vT16 + (size_t)(b * 8 + h) * 65536;
  // Q fragments (register-resident all kernel)
  bf16x8 aQ[2];
  {
    const unsigned short* qsrc =
        q16h + ((size_t)((b * 8 + h) * 512 + qb + ws4 * 16 + ln)) * 64;
    aQ[0] = ldb16x8(qsrc + qd * 8);
    aQ[1] = ldb16x8(qsrc + 32 + qd * 8);
  }
  f32x4 z = {0.f, 0.f, 0.f, 0.f};
  f32x4 acc[4] = {z, z, z, z};

  for (int kti = 0; kti < 8; ++kti) {
    {  // stage: squad (t>>8) stages buffer for its kt half
      int u = t & 255, gg = t >> 8;
      int kt0s = (kti + gg * 8) << 6;
      unsigned short* rt_ = reltile + gg * 4352;
      unsigned short* kp_ = kpws + gg * 2304;
      int qr = u >> 2, cg = (u & 3) << 4;
      const int* rp = rel + ((size_t)(b * 512 + qb + qr)) * 1024 + kt0s + cg;
      const unsigned char* mp = mask + ((size_t)(b * 512 + qb + qr)) * 1024 + kt0s + cg;
      int4 r4[4];
      r4[0] = ((const int4*)rp)[0]; r4[1] = ((const int4*)rp)[1];
      r4[2] = ((const int4*)rp)[2]; r4[3] = ((const int4*)rp)[3];
      uint4 mu = *(const uint4*)mp;
      const unsigned char* mb = (const unsigned char*)&mu;
      const int* ri = (const int*)r4;
#pragma unroll
      for (int j4 = 0; j4 < 4; ++j4) {
        ushort4 pk;
        pk.x = (unsigned short)(ri[j4 * 4 + 0] | (mb[j4 * 4 + 0] ? 0x8000 : 0));
        pk.y = (unsigned short)(ri[j4 * 4 + 1] | (mb[j4 * 4 + 1] ? 0x8000 : 0));
        pk.z = (unsigned short)(ri[j4 * 4 + 2] | (mb[j4 * 4 + 2] ? 0x8000 : 0));
        pk.w = (unsigned short)(ri[j4 * 4 + 3] | (mb[j4 * 4 + 3] ? 0x8000 : 0));
        *(ushort4*)&rt_[qr * 68 + cg + j4 * 4] = pk;
      }
      int krow = u >> 2, kc8 = (u & 3) << 3;
      const float* kpp = kpw + ((size_t)((b * 8 + h) * 1024) + kt0s + krow) * 32 + kc8;
      float4 f0 = *(const float4*)kpp;
      float4 f1 = *(const float4*)(kpp + 4);
      ushort4 u0, u1;
      u0.x = f2bf(f0.x); u0.y = f2bf(f0.y); u0.z = f2bf(f0.z); u0.w = f2bf(f0.w);
      u1.x = f2bf(f1.x); u1.y = f2bf(f1.y); u1.z = f2bf(f1.z); u1.w = f2bf(f1.w);
      *(ushort4*)&kp_[krow * 36 + kc8] = u0;
      *(ushort4*)&kp_[krow * 36 + kc8 + 4] = u1;
    }
    __syncthreads();
    const int kt0 = (kti + g * 8) << 6;

    // ---- QK^T: B-frags straight from global (L2) ----
    f32x4 sc4[4];
#pragma unroll
    for (int t4 = 0; t4 < 4; ++t4) {
      f32x4 c = z;
      c = MFMA16(aQ[0], ldb16x8(kbase + (size_t)(kt0 + t4 * 16 + ln) * 64 + qd * 8), c);
      c = MFMA16(aQ[1], ldb16x8(kbase + (size_t)(kt0 + t4 * 16 + ln) * 64 + 32 + qd * 8), c);
      sc4[t4] = c;
    }

    // ---- bias + scale + mask + exp; vdw scatter; P -> pbuf ----
    unsigned short* rt_ = reltile + g * 4352;
    unsigned short* kp_ = kpws + g * 2304;
#pragma unroll
    for (int r = 0; r < 4; ++r) {
#pragma unroll
      for (int t4 = 0; t4 < 4; ++t4) {
        int row_l = ws4 * 16 + qd * 4 + r;
        int kl = t4 * 16 + ln;
        unsigned um = rt_[row_l * 68 + kl];
        int rd = um & 31;
        float s = (sc4[t4][r] + b2f(q32s[row_l * 36 + rd]) + b2f(kp_[kl * 36 + rd])) * 0.125f;
        float p = (um & 0x8000u) ? 0.f : __expf(s);
        atomicAdd(&vdwm[ws4 * 576 + (qd * 4 + r) * 36 + rd], p);
        pbuf[w * 1152 + (qd * 4 + r) * 72 + kl] = f2bf(p);
      }
    }

    // ---- PV: O += P(16x64) @ V(64x64); V-frags from global (L2) ----
    bf16x8 a0 = ldb16x8(&pbuf[w * 1152 + ln * 72 + qd * 8]);
    bf16x8 a1 = ldb16x8(&pbuf[w * 1152 + ln * 72 + 32 + qd * 8]);
#pragma unroll
    for (int dt = 0; dt < 4; ++dt) {
      acc[dt] = MFMA16(a0, ldb16x8(vbase + (size_t)(dt * 16 + ln) * 1024 + kt0 + qd * 8), acc[dt]);
      acc[dt] = MFMA16(a1, ldb16x8(vbase + (size_t)(dt * 16 + ln) * 1024 + kt0 + 32 + qd * 8), acc[dt]);
    }
    __syncthreads();
  }

  // ---- endgame: vest staged by g0 threads, vdwb built by g1 waves ----
  if (t < 256) {
    int n = t >> 3, d0 = (t & 7) << 3;
    const float* src = v_emb + ((size_t)n << 9) + (h << 6) + d0;
    float4 f0 = *(const float4*)src;
    float4 f1 = *(const float4*)(src + 4);
    vest[(d0 + 0) * 40 + n] = f2bf(f0.x); vest[(d0 + 1) * 40 + n] = f2bf(f0.y);
    vest[(d0 + 2) * 40 + n] = f2bf(f0.z); vest[(d0 + 3) * 40 + n] = f2bf(f0.w);
    vest[(d0 + 4) * 40 + n] = f2bf(f1.x); vest[(d0 + 5) * 40 + n] = f2bf(f1.y);
    vest[(d0 + 6) * 40 + n] = f2bf(f1.z); vest[(d0 + 7) * 40 + n] = f2bf(f1.w);
  } else {
    int row = lane >> 2, n0 = (lane & 3) << 3;
    float4 v0 = *(const float4*)&vdwm[ws4 * 576 + row * 36 + n0];
    float4 v1 = *(const float4*)&vdwm[ws4 * 576 + row * 36 + n0 + 4];
    ushort4 u0, u1;
    u0.x = f2bf(v0.x); u0.y = f2bf(v0.y); u0.z = f2bf(v0.z); u0.w = f2bf(v0.w);
    u1.x = f2bf(v1.x); u1.y = f2bf(v1.y); u1.z = f2bf(v1.z); u1.w = f2bf(v1.w);
    *(ushort4*)&vdwb[ws4 * 640 + row * 40 + n0] = u0;
    *(ushort4*)&vdwb[ws4 * 640 + row * 40 + n0 + 4] = u1;
  }
  __syncthreads();

  if (g == 1) {  // add vdw @ v_emb into g1 partial, publish partial O
    bf16x8 av = ldb16x8(&vdwb[ws4 * 640 + ln * 40 + qd * 8]);
#pragma unroll
    for (int dt = 0; dt < 4; ++dt)
      acc[dt] = MFMA16(av, ldb16x8(&vest[(dt * 16 + ln) * 40 + qd * 8]), acc[dt]);
#pragma unroll
    for (int r = 0; r < 4; ++r)
#pragma unroll
      for (int dt = 0; dt < 4; ++dt)
        accbuf[ws4 * 1088 + (qd * 4 + r) * 68 + dt * 16 + ln] = acc[dt][r];
  }
  __syncthreads();

  if (g == 0) {  // combine, normalize, store bf16
    float inv[4];
#pragma unroll
    for (int r = 0; r < 4; ++r) {
      float l = 0.f;
#pragma unroll
      for (int n4 = 0; n4 < 8; ++n4) {
        float4 v = *(const float4*)&vdwm[ws4 * 576 + (qd * 4 + r) * 36 + (n4 << 2)];
        l += v.x + v.y + v.z + v.w;
      }
      inv[r] = 1.f / l;
    }
    unsigned short* obase =
        attn16 + ((size_t)(b * 512 + qb + ws4 * 16 + qd * 4)) * 512 + (h << 6);
#pragma unroll
    for (int r = 0; r < 4; ++r)
#pragma unroll
      for (int dt = 0; dt < 4; ++dt) {
        float v = (acc[dt][r] + accbuf[ws4 * 1088 + (qd * 4 + r) * 68 + dt * 16 + ln]) * inv[r];
        obase[(size_t)r * 512 + dt * 16 + ln] = f2bf(v);
      }
  }
}

// ---------------------------------------------------------------------------
extern "C" void kernel_launch(void* const* d_in, const int* in_sizes, int n_in,
                              void* d_out, int out_size, void* d_ws, size_t ws_size,
                              hipStream_t stream) {
  const float* x = (const float*)d_in[0];
  const int* rel = (const int*)d_in[1];
  const unsigned char* mask = (const unsigned char*)d_in[2];
  const float* qpe = (const float*)d_in[3];
  const float* kpe = (const float*)d_in[4];
  const float* vpe = (const float*)d_in[5];
  const float* Wq = (const float*)d_in[6];
  const float* Wk = (const float*)d_in[7];
  const float* Wv = (const float*)d_in[8];
  const float* Wo = (const float*)d_in[9];
  float* out = (float*)d_out;

  float* ws = (float*)d_ws;
  float* qpw = ws;                                   // 1,048,576 f
  float* kpw = qpw + 1048576;                        // 2,097,152 f
  unsigned short* kb16 = (unsigned short*)(kpw + 2097152);   // 4,194,304 u (2,097,152 f)
  unsigned short* vT16 = kb16 + 4194304;             // 4,194,304 u
  unsigned short* q16h = vT16 + 4194304;             // 2,097,152 u
  unsigned short* attn16 = q16h + 2097152;           // 2,097,152 u
  unsigned short* x16 = attn16 + 2097152;            // 2,097,152 u
  unsigned short* w16q = x16 + 2097152;              //   262,144 u
  unsigned short* w16k = w16q + 262144;              //   524,288 u
  unsigned short* w16v = w16k + 524288;              //   524,288 u
  unsigned short* w16o = w16v + 524288;              //   262,144 u  -> ~45 MB total

  cvt5_k<<<3584, 256, 0, stream>>>(x, Wq, Wk, Wv, Wo, x16, w16q, w16k, w16v, w16o);
  gemm16_k<1><<<dim3(8, 64), 256, 0, stream>>>(x16, w16q, q16h, 4096, 512, 512);
  gemm16_k<2><<<dim3(16, 64), 256, 0, stream>>>(x16, w16k, kb16, 4096, 1024, 512);
  gemm16_k<3><<<dim3(16, 64), 256, 0, stream>>>(x16, w16v, vT16, 4096, 1024, 512);
  posw16_k<<<8 * 8 * 8, 256, 0, stream>>>(q16h, qpe, qpw, 512);
  posw16_k<<<8 * 8 * 16, 256, 0, stream>>>(kb16, kpe, kpw, 1024);
  attn3_k<<<512, 512, 0, stream>>>(q16h, kb16, vT16, qpw, kpw, rel, mask, vpe, attn16);
  gemm16_k<0><<<dim3(8, 64), 256, 0, stream>>>(attn16, w16o, out, 4096, 512, 512);
}

// Round 5
// 366.084 us; speedup vs baseline: 3.2756x; 1.0037x over previous
//
#include <hip/hip_runtime.h>
#include <math.h>

#define Bc 8
#define Sc 512
#define Hc 512
#define NHc 8
#define HDc 64
#define DISc 32
#define S2c 1024

typedef __attribute__((ext_vector_type(8))) short bf16x8;
typedef __attribute__((ext_vector_type(4))) float f32x4;
#define MFMA16(a, b, c) __builtin_amdgcn_mfma_f32_16x16x32_bf16(a, b, c, 0, 0, 0)

__device__ __forceinline__ unsigned short f2bf(float f) {
  unsigned u = __float_as_uint(f);
  return (unsigned short)((u + 0x7fffu + ((u >> 16) & 1u)) >> 16);  // RNE
}
__device__ __forceinline__ float b2f(unsigned short u) {
  return __uint_as_float((unsigned)u << 16);
}
__device__ __forceinline__ bf16x8 ldb16x8(const unsigned short* p) {
  union { uint4 u; bf16x8 s; } cv;
  cv.u = *(const uint4*)p;
  return cv.s;
}

// ---------------------------------------------------------------------------
// fp32 -> bf16 conversions for x, Wq, Wk, Wv, Wo (one fused launch).
// ---------------------------------------------------------------------------
__global__ __launch_bounds__(256) void cvt5_k(
    const float* __restrict__ x, const float* __restrict__ wq,
    const float* __restrict__ wk, const float* __restrict__ wv,
    const float* __restrict__ wo, unsigned short* __restrict__ x16,
    unsigned short* __restrict__ w16q, unsigned short* __restrict__ w16k,
    unsigned short* __restrict__ w16v, unsigned short* __restrict__ w16o) {
  int i = blockIdx.x * 256 + threadIdx.x;
  const float* src; unsigned short* dst; int off;
  if (i < 524288)      { src = x;  dst = x16;  off = i; }
  else if (i < 589824) { src = wq; dst = w16q; off = i - 524288; }
  else if (i < 720896) { src = wk; dst = w16k; off = i - 589824; }
  else if (i < 851968) { src = wv; dst = w16v; off = i - 720896; }
  else                 { src = wo; dst = w16o; off = i - 851968; }
  float4 v = ((const float4*)src)[off];
  ushort4 u;
  u.x = f2bf(v.x); u.y = f2bf(v.y); u.z = f2bf(v.z); u.w = f2bf(v.w);
  ((ushort4*)dst)[off] = u;
}

// ---------------------------------------------------------------------------
// Pack rel (int32 0..31) + mask (u8) -> u8 (rd | m<<7). 4M elems, 16/thread.
// ---------------------------------------------------------------------------
__global__ __launch_bounds__(256) void pack_k(const int* __restrict__ rel,
                                              const unsigned char* __restrict__ mask,
                                              unsigned char* __restrict__ pk8) {
  int i = blockIdx.x * 256 + threadIdx.x;      // 262144 threads
  const int* rp = rel + i * 16;
  uint4 mu = *(const uint4*)(mask + i * 16);
  const unsigned char* mb = (const unsigned char*)&mu;
  uint4 o;
  unsigned* ow = (unsigned*)&o;
#pragma unroll
  for (int g = 0; g < 4; ++g) {
    int4 r4 = ((const int4*)rp)[g];
    unsigned b0 = ((unsigned)r4.x & 31u) | (mb[g * 4 + 0] ? 0x80u : 0u);
    unsigned b1 = ((unsigned)r4.y & 31u) | (mb[g * 4 + 1] ? 0x80u : 0u);
    unsigned b2 = ((unsigned)r4.z & 31u) | (mb[g * 4 + 2] ? 0x80u : 0u);
    unsigned b3 = ((unsigned)r4.w & 31u) | (mb[g * 4 + 3] ? 0x80u : 0u);
    ow[g] = b0 | (b1 << 8) | (b2 << 16) | (b3 << 24);
  }
  *(uint4*)(pk8 + i * 16) = o;
}

// ---------------------------------------------------------------------------
// bf16 MFMA GEMM: C[M,N] = A16[M,K] @ B16[N,K]^T, fp32 accumulate.
// 64x64 tile, BK=32, block 256 (4 waves 2x2, wave tile 32x32).
// MODE 0: fp32 C | 1: q16h[b][h][s][d] | 2: kb16[b][h][k2][d] | 3: vT16[b][h][d][k2]
// ---------------------------------------------------------------------------
template <int MODE>
__global__ __launch_bounds__(256, 4) void gemm16_k(
    const unsigned short* __restrict__ A, const unsigned short* __restrict__ B,
    void* __restrict__ outp, int M, int N, int K) {
  const int t = threadIdx.x;
  const int w = t >> 6, lane = t & 63, ln = lane & 15, qd = lane >> 4;
  const int wm = (w >> 1) << 5, wn = (w & 1) << 5;
  const int m0 = blockIdx.y << 6, n0 = blockIdx.x << 6;
  __shared__ unsigned short As[64 * 32];
  __shared__ unsigned short Bs[64 * 32];
  f32x4 z = {0.f, 0.f, 0.f, 0.f};
  f32x4 acc[2][2] = {{z, z}, {z, z}};
  const int srow = t >> 2, sc8 = (t & 3) << 3;
  for (int k0 = 0; k0 < K; k0 += 32) {
    *(uint4*)&As[srow * 32 + sc8] = *(const uint4*)(A + (size_t)(m0 + srow) * K + k0 + sc8);
    *(uint4*)&Bs[srow * 32 + sc8] = *(const uint4*)(B + (size_t)(n0 + srow) * K + k0 + sc8);
    __syncthreads();
    bf16x8 a0 = ldb16x8(&As[(wm + ln) * 32 + qd * 8]);
    bf16x8 a1 = ldb16x8(&As[(wm + 16 + ln) * 32 + qd * 8]);
    bf16x8 b0 = ldb16x8(&Bs[(wn + ln) * 32 + qd * 8]);
    bf16x8 b1 = ldb16x8(&Bs[(wn + 16 + ln) * 32 + qd * 8]);
    acc[0][0] = MFMA16(a0, b0, acc[0][0]);
    acc[0][1] = MFMA16(a0, b1, acc[0][1]);
    acc[1][0] = MFMA16(a1, b0, acc[1][0]);
    acc[1][1] = MFMA16(a1, b1, acc[1][1]);
    __syncthreads();
  }
#pragma unroll
  for (int tm = 0; tm < 2; ++tm)
#pragma unroll
    for (int tn = 0; tn < 2; ++tn)
#pragma unroll
      for (int r = 0; r < 4; ++r) {
        int m = m0 + wm + tm * 16 + qd * 4 + r;
        int n = n0 + wn + tn * 16 + ln;
        float v = acc[tm][tn][r];
        if (MODE == 0) {
          ((float*)outp)[(size_t)m * N + n] = v;
        } else {
          int bb = m >> 9, s = m & 511, hh = (n >> 6) & 7, d = n & 63;
          if (MODE == 1)
            ((unsigned short*)outp)[((size_t)(bb * 8 + hh) * 512 + s) * 64 + d] = f2bf(v);
          else if (MODE == 2) {
            int k2 = 2 * s + (n >> 9);
            ((unsigned short*)outp)[((size_t)(bb * 8 + hh) * 1024 + k2) * 64 + d] = f2bf(v);
          } else {
            int k2 = 2 * s + (n >> 9);
            ((unsigned short*)outp)[((size_t)(bb * 8 + hh) * 64 + d) * 1024 + k2] = f2bf(v);
          }
        }
      }
}

// ---------------------------------------------------------------------------
// Pos-weight tables from bf16 h-major rows.
// ---------------------------------------------------------------------------
__global__ __launch_bounds__(256) void posw16_k(const unsigned short* __restrict__ rows16,
                                                const float* __restrict__ emb,
                                                float* __restrict__ out, int R) {
  const int t = threadIdx.x;
  const int tiles = R >> 6;
  const int rt = blockIdx.x % tiles;
  const int h = (blockIdx.x / tiles) & 7;
  const int b = blockIdx.x / (tiles * 8);
  __shared__ float es[32][65];
  __shared__ float xs[64][65];
#pragma unroll
  for (int i = 0; i < 2; ++i) {
    int f = t + (i << 8);
    int n = f >> 4, d4 = (f & 15) << 2;
    float4 v4 = *(const float4*)(emb + ((size_t)n << 9) + (h << 6) + d4);
    es[n][d4] = v4.x; es[n][d4 + 1] = v4.y; es[n][d4 + 2] = v4.z; es[n][d4 + 3] = v4.w;
  }
  const size_t row0 = (size_t)(b * 8 + h) * R + (rt << 6);
#pragma unroll
  for (int p = 0; p < 2; ++p) {
    int id = t + (p << 8);
    int r = id >> 3, c8 = (id & 7) << 3;
    uint4 u4 = *(const uint4*)(rows16 + (row0 + r) * 64 + c8);
    const unsigned short* us = (const unsigned short*)&u4;
#pragma unroll
    for (int j = 0; j < 8; ++j) xs[r][c8 + j] = b2f(us[j]);
  }
  __syncthreads();
  const int n = t & 31;
  const int rs0 = (t >> 5) << 3;
  for (int rr = 0; rr < 8; ++rr) {
    float s = 0.f;
#pragma unroll
    for (int d = 0; d < 64; ++d) s = fmaf(xs[rs0 + rr][d], es[n][d], s);
    out[((((size_t)b * 8 + h) * R) + (rt << 6) + rs0 + rr) * 32 + n] = s;
  }
}

// ---------------------------------------------------------------------------
// MFMA attention, split-K wave groups + XCD-swizzled grid (bid%8 = b so each
// batch's rel/K/V working set stays inside one XCD's L2).
// Block = (b,h,64 q), 512 thr = 8 waves; g0: kt 0-7, g1: kt 8-15.
// Raw-exp accumulate (scores bounded), normalize once at the end.
// ---------------------------------------------------------------------------
__global__ __launch_bounds__(512, 4) void attn4_k(
    const unsigned short* __restrict__ q16h, const unsigned short* __restrict__ kb16,
    const unsigned short* __restrict__ vT16, const float* __restrict__ qpw,
    const float* __restrict__ kpw, const unsigned char* __restrict__ pk8,
    const float* __restrict__ v_emb, unsigned short* __restrict__ attn16) {
  const int bid = blockIdx.x;
  const int b = bid & 7;                 // XCD-affine: bid%8 == b
  const int h = (bid >> 3) & 7;
  const int qb = ((bid >> 6) & 7) << 6;
  const int t = threadIdx.x;
  const int w = t >> 6;
  const int g = w >> 2;
  const int ws4 = w & 3;
  const int lane = t & 63;
  const int ln = lane & 15;
  const int qd = lane >> 4;

  __shared__ __align__(16) char smem[51712];
  unsigned char*  pkt  = (unsigned char*)smem;                // 2 x (64x80) u8
  unsigned short* kpws = (unsigned short*)(smem + 10240);     // 2 x (64x36) u16
  unsigned short* q32s = (unsigned short*)(smem + 19456);     // 64x36 u16
  unsigned short* pbuf = (unsigned short*)(smem + 24064);     // 8 x (16x72) u16
  float*          vdwm = (float*)(smem + 42496);              // 4 x (16x36) f
  // endgame aliases (source regions dead by then):
  float*          accbuf = (float*)smem;                      // 4 x (16x68) f (pkt+kpws dead)
  unsigned short* vest   = (unsigned short*)(smem + 24064);   // 64x40 u16 (pbuf dead)
  unsigned short* vdwb   = (unsigned short*)(smem + 29184);   // 4 x (16x40) u16

  for (int i = t; i < 4 * 16 * 36; i += 512) vdwm[i] = 0.f;
  {  // q32s: 64 q x 32 n, fp32 -> bf16
    const float* src = qpw + ((size_t)((b * 8 + h) * 512 + qb)) * 32;
    int row = t >> 3, c4 = (t & 7) << 2;
    float4 v = *(const float4*)(src + row * 32 + c4);
    ushort4 u;
    u.x = f2bf(v.x); u.y = f2bf(v.y); u.z = f2bf(v.z); u.w = f2bf(v.w);
    *(ushort4*)&q32s[row * 36 + c4] = u;
  }
  const unsigned short* kbase = kb16 + (size_t)(b * 8 + h) * 65536;
  const unsigned short* vbase = vT16 + (size_t)(b * 8 + h) * 65536;
  bf16x8 aQ[2];
  {
    const unsigned short* qsrc =
        q16h + ((size_t)((b * 8 + h) * 512 + qb + ws4 * 16 + ln)) * 64;
    aQ[0] = ldb16x8(qsrc + qd * 8);
    aQ[1] = ldb16x8(qsrc + 32 + qd * 8);
  }
  f32x4 z = {0.f, 0.f, 0.f, 0.f};
  f32x4 acc[4] = {z, z, z, z};

  for (int kti = 0; kti < 8; ++kti) {
    {  // stage: squad (t>>8) stages its kt half: packed rel/mask + kpw
      int u = t & 255, gg = t >> 8;
      int kt0s = (kti + gg * 8) << 6;
      unsigned char* pt_ = pkt + gg * 5120;
      unsigned short* kp_ = kpws + gg * 2304;
      int qr = u >> 2, cg = (u & 3) << 4;
      uint4 pv = *(const uint4*)(pk8 + ((size_t)(b * 512 + qb + qr)) * 1024 + kt0s + cg);
      *(uint4*)&pt_[qr * 80 + cg] = pv;
      int krow = u >> 2, kc8 = (u & 3) << 3;
      const float* kpp = kpw + ((size_t)((b * 8 + h) * 1024) + kt0s + krow) * 32 + kc8;
      float4 f0 = *(const float4*)kpp;
      float4 f1 = *(const float4*)(kpp + 4);
      ushort4 u0, u1;
      u0.x = f2bf(f0.x); u0.y = f2bf(f0.y); u0.z = f2bf(f0.z); u0.w = f2bf(f0.w);
      u1.x = f2bf(f1.x); u1.y = f2bf(f1.y); u1.z = f2bf(f1.z); u1.w = f2bf(f1.w);
      *(ushort4*)&kp_[krow * 36 + kc8] = u0;
      *(ushort4*)&kp_[krow * 36 + kc8 + 4] = u1;
    }
    __syncthreads();
    const int kt0 = (kti + g * 8) << 6;

    // ---- QK^T: B-frags straight from global (same-XCD L2) ----
    f32x4 sc4[4];
#pragma unroll
    for (int t4 = 0; t4 < 4; ++t4) {
      f32x4 c = z;
      c = MFMA16(aQ[0], ldb16x8(kbase + (size_t)(kt0 + t4 * 16 + ln) * 64 + qd * 8), c);
      c = MFMA16(aQ[1], ldb16x8(kbase + (size_t)(kt0 + t4 * 16 + ln) * 64 + 32 + qd * 8), c);
      sc4[t4] = c;
    }

    // ---- bias + scale + mask + exp; vdw scatter; P -> pbuf ----
    unsigned char* pt_ = pkt + g * 5120;
    unsigned short* kp_ = kpws + g * 2304;
#pragma unroll
    for (int r = 0; r < 4; ++r) {
#pragma unroll
      for (int t4 = 0; t4 < 4; ++t4) {
        int row_l = ws4 * 16 + qd * 4 + r;
        int kl = t4 * 16 + ln;
        unsigned um = pt_[row_l * 80 + kl];
        int rd = um & 31;
        float s = (sc4[t4][r] + b2f(q32s[row_l * 36 + rd]) + b2f(kp_[kl * 36 + rd])) * 0.125f;
        float p = (um & 0x80u) ? 0.f : __expf(s);
        atomicAdd(&vdwm[ws4 * 576 + (qd * 4 + r) * 36 + rd], p);
        pbuf[w * 1152 + (qd * 4 + r) * 72 + kl] = f2bf(p);
      }
    }

    // ---- PV: O += P(16x64) @ V(64x64); V-frags from global (L2) ----
    bf16x8 a0 = ldb16x8(&pbuf[w * 1152 + ln * 72 + qd * 8]);
    bf16x8 a1 = ldb16x8(&pbuf[w * 1152 + ln * 72 + 32 + qd * 8]);
#pragma unroll
    for (int dt = 0; dt < 4; ++dt) {
      acc[dt] = MFMA16(a0, ldb16x8(vbase + (size_t)(dt * 16 + ln) * 1024 + kt0 + qd * 8), acc[dt]);
      acc[dt] = MFMA16(a1, ldb16x8(vbase + (size_t)(dt * 16 + ln) * 1024 + kt0 + 32 + qd * 8), acc[dt]);
    }
    __syncthreads();
  }

  // ---- endgame: vest staged by g0 threads, vdwb built by g1 waves ----
  if (t < 256) {
    int n = t >> 3, d0 = (t & 7) << 3;
    const float* src = v_emb + ((size_t)n << 9) + (h << 6) + d0;
    float4 f0 = *(const float4*)src;
    float4 f1 = *(const float4*)(src + 4);
    vest[(d0 + 0) * 40 + n] = f2bf(f0.x); vest[(d0 + 1) * 40 + n] = f2bf(f0.y);
    vest[(d0 + 2) * 40 + n] = f2bf(f0.z); vest[(d0 + 3) * 40 + n] = f2bf(f0.w);
    vest[(d0 + 4) * 40 + n] = f2bf(f1.x); vest[(d0 + 5) * 40 + n] = f2bf(f1.y);
    vest[(d0 + 6) * 40 + n] = f2bf(f1.z); vest[(d0 + 7) * 40 + n] = f2bf(f1.w);
  } else {
    int row = lane >> 2, n0 = (lane & 3) << 3;
    float4 v0 = *(const float4*)&vdwm[ws4 * 576 + row * 36 + n0];
    float4 v1 = *(const float4*)&vdwm[ws4 * 576 + row * 36 + n0 + 4];
    ushort4 u0, u1;
    u0.x = f2bf(v0.x); u0.y = f2bf(v0.y); u0.z = f2bf(v0.z); u0.w = f2bf(v0.w);
    u1.x = f2bf(v1.x); u1.y = f2bf(v1.y); u1.z = f2bf(v1.z); u1.w = f2bf(v1.w);
    *(ushort4*)&vdwb[ws4 * 640 + row * 40 + n0] = u0;
    *(ushort4*)&vdwb[ws4 * 640 + row * 40 + n0 + 4] = u1;
  }
  __syncthreads();

  if (g == 1) {  // add vdw @ v_emb into g1 partial, publish partial O
    bf16x8 av = ldb16x8(&vdwb[ws4 * 640 + ln * 40 + qd * 8]);
#pragma unroll
    for (int dt = 0; dt < 4; ++dt)
      acc[dt] = MFMA16(av, ldb16x8(&vest[(dt * 16 + ln) * 40 + qd * 8]), acc[dt]);
#pragma unroll
    for (int r = 0; r < 4; ++r)
#pragma unroll
      for (int dt = 0; dt < 4; ++dt)
        accbuf[ws4 * 1088 + (qd * 4 + r) * 68 + dt * 16 + ln] = acc[dt][r];
  }
  __syncthreads();

  if (g == 0) {  // combine, normalize, store bf16
    float inv[4];
#pragma unroll
    for (int r = 0; r < 4; ++r) {
      float l = 0.f;
#pragma unroll
      for (int n4 = 0; n4 < 8; ++n4) {
        float4 v = *(const float4*)&vdwm[ws4 * 576 + (qd * 4 + r) * 36 + (n4 << 2)];
        l += v.x + v.y + v.z + v.w;
      }
      inv[r] = 1.f / l;
    }
    unsigned short* obase =
        attn16 + ((size_t)(b * 512 + qb + ws4 * 16 + qd * 4)) * 512 + (h << 6);
#pragma unroll
    for (int r = 0; r < 4; ++r)
#pragma unroll
      for (int dt = 0; dt < 4; ++dt) {
        float v = (acc[dt][r] + accbuf[ws4 * 1088 + (qd * 4 + r) * 68 + dt * 16 + ln]) * inv[r];
        obase[(size_t)r * 512 + dt * 16 + ln] = f2bf(v);
      }
  }
}

// ---------------------------------------------------------------------------
extern "C" void kernel_launch(void* const* d_in, const int* in_sizes, int n_in,
                              void* d_out, int out_size, void* d_ws, size_t ws_size,
                              hipStream_t stream) {
  const float* x = (const float*)d_in[0];
  const int* rel = (const int*)d_in[1];
  const unsigned char* mask = (const unsigned char*)d_in[2];
  const float* qpe = (const float*)d_in[3];
  const float* kpe = (const float*)d_in[4];
  const float* vpe = (const float*)d_in[5];
  const float* Wq = (const float*)d_in[6];
  const float* Wk = (const float*)d_in[7];
  const float* Wv = (const float*)d_in[8];
  const float* Wo = (const float*)d_in[9];
  float* out = (float*)d_out;

  float* ws = (float*)d_ws;
  float* qpw = ws;                                   // 1,048,576 f
  float* kpw = qpw + 1048576;                        // 2,097,152 f
  unsigned short* kb16 = (unsigned short*)(kpw + 2097152);   // 4,194,304 u16
  unsigned short* vT16 = kb16 + 4194304;             // 4,194,304 u16
  unsigned short* q16h = vT16 + 4194304;             // 2,097,152 u16
  unsigned short* attn16 = q16h + 2097152;           // 2,097,152 u16
  unsigned short* x16 = attn16 + 2097152;            // 2,097,152 u16
  unsigned short* w16q = x16 + 2097152;              //   262,144 u16
  unsigned short* w16k = w16q + 262144;              //   524,288 u16
  unsigned short* w16v = w16k + 524288;              //   524,288 u16
  unsigned short* w16o = w16v + 524288;              //   262,144 u16
  unsigned char* pk8 = (unsigned char*)(w16o + 262144);  // 4,194,304 u8 -> ~49 MB

  pack_k<<<1024, 256, 0, stream>>>(rel, mask, pk8);
  cvt5_k<<<3584, 256, 0, stream>>>(x, Wq, Wk, Wv, Wo, x16, w16q, w16k, w16v, w16o);
  gemm16_k<1><<<dim3(8, 64), 256, 0, stream>>>(x16, w16q, q16h, 4096, 512, 512);
  gemm16_k<2><<<dim3(16, 64), 256, 0, stream>>>(x16, w16k, kb16, 4096, 1024, 512);
  gemm16_k<3><<<dim3(16, 64), 256, 0, stream>>>(x16, w16v, vT16, 4096, 1024, 512);
  posw16_k<<<8 * 8 * 8, 256, 0, stream>>>(q16h, qpe, qpw, 512);
  posw16_k<<<8 * 8 * 16, 256, 0, stream>>>(kb16, kpe, kpw, 1024);
  attn4_k<<<512, 512, 0, stream>>>(q16h, kb16, vT16, qpw, kpw, pk8, vpe, attn16);
  gemm16_k<0><<<dim3(8, 64), 256, 0, stream>>>(attn16, w16o, out, 4096, 512, 512);
}